// Round 2
// baseline (60.992 us; speedup 1.0000x reference)
//
#include <hip/hip_runtime.h>

#define SPB 32   // samples per block
#define NT  320  // threads = SPB * 10 rows

__global__ __launch_bounds__(NT, 2)
void crazy_attn_kernel(const float* __restrict__ state,      // (B,100)
                       const float* __restrict__ pos_intra,  // (10,1)
                       const float* __restrict__ wq_i, const float* __restrict__ bq_i,
                       const float* __restrict__ wk_i, const float* __restrict__ bk_i,
                       const float* __restrict__ wv_i, const float* __restrict__ bv_i,
                       const float* __restrict__ pos_inter,  // (10,20)
                       const float* __restrict__ wq, const float* __restrict__ bq,
                       const float* __restrict__ wk, const float* __restrict__ bk,
                       const float* __restrict__ wv, const float* __restrict__ bv,
                       float* __restrict__ out, int B)
{
    // per sample: k rows @0 (10 x 24), v rows @240 (10 x 24), +4 skew
    // sample stride 484 floats: 484 % 32 == 4  -> 7 samples/wave spread over
    // 28 banks, 10 same-sample lanes broadcast => conflict-free b128 reads.
    __attribute__((aligned(16))) __shared__ float s_kv[SPB * 484];

    const int tid  = threadIdx.x;
    const int samp = tid / 10;
    const int r    = tid - samp * 10;   // frame index == inter row index
    const int gs   = blockIdx.x * SPB + samp;
    const int gsc  = (gs < B) ? gs : (B - 1);   // clamp for loads

    // ---------------- stage A: intra attention (all in registers) ----------
    float x[20];
    {
        const float* sp = state + (size_t)gsc * 100 + r * 10;
        float xv[10];
        #pragma unroll
        for (int t = 0; t < 10; ++t) xv[t] = sp[t] + pos_intra[t];  // pos_intra: uniform s_load

        #pragma unroll
        for (int h = 0; h < 2; ++h) {
            const float wqh = wq_i[h], bqh = bq_i[h];
            const float wkh = wk_i[h], bkh = bk_i[h];
            const float wvh = wv_i[h], bvh = bv_i[h];
            float qh[10], kh[10], vh[10];
            #pragma unroll
            for (int t = 0; t < 10; ++t) {
                qh[t] = fmaf(xv[t], wqh, bqh);
                kh[t] = fmaf(xv[t], wkh, bkh);
                vh[t] = fmaf(xv[t], wvh, bvh);
            }
            #pragma unroll
            for (int s = 0; s < 10; ++s) {
                float sc[10], m = -1e30f;
                #pragma unroll
                for (int t = 0; t < 10; ++t) { sc[t] = qh[s] * kh[t]; m = fmaxf(m, sc[t]); }
                float sum = 0.f, o = 0.f;
                #pragma unroll
                for (int t = 0; t < 10; ++t) {
                    const float e = __expf(sc[t] - m);
                    sum += e; o = fmaf(e, vh[t], o);
                }
                x[s * 2 + h] = o / sum;
            }
        }
        // learned positional embedding for inter stage (per-lane r -> VMEM, L1-hot)
        #pragma unroll
        for (int c = 0; c < 20; ++c) x[c] += pos_inter[r * 20 + c];
    }

    // ---------------- stage B: projections; weights via uniform scalar loads
    float* kvbase = &s_kv[samp * 484];

    float q[21];
    #pragma unroll
    for (int c = 0; c < 21; ++c) q[c] = bq[c];
    #pragma unroll
    for (int j = 0; j < 20; ++j) {
        const float xj = x[j];
        #pragma unroll
        for (int c = 0; c < 21; ++c) q[c] = fmaf(xj, wq[j * 21 + c], q[c]);
    }
    {   // k row -> LDS
        float kr[24];
        #pragma unroll
        for (int c = 0; c < 21; ++c) kr[c] = bk[c];
        kr[21] = kr[22] = kr[23] = 0.f;
        #pragma unroll
        for (int j = 0; j < 20; ++j) {
            const float xj = x[j];
            #pragma unroll
            for (int c = 0; c < 21; ++c) kr[c] = fmaf(xj, wk[j * 21 + c], kr[c]);
        }
        #pragma unroll
        for (int i = 0; i < 6; ++i)
            *(float4*)&kvbase[r * 24 + i * 4] = *(const float4*)&kr[i * 4];
    }
    {   // v row -> LDS
        float vr[24];
        #pragma unroll
        for (int c = 0; c < 21; ++c) vr[c] = bv[c];
        vr[21] = vr[22] = vr[23] = 0.f;
        #pragma unroll
        for (int j = 0; j < 20; ++j) {
            const float xj = x[j];
            #pragma unroll
            for (int c = 0; c < 21; ++c) vr[c] = fmaf(xj, wv[j * 21 + c], vr[c]);
        }
        #pragma unroll
        for (int i = 0; i < 6; ++i)
            *(float4*)&kvbase[240 + r * 24 + i * 4] = *(const float4*)&vr[i * 4];
    }

    __syncthreads();   // the only barrier

    // ---------------- stage C: inter attention (q in regs, k/v from LDS) ---
    float sc[10], m = -1e30f;
    #pragma unroll
    for (int t = 0; t < 10; ++t) {
        float kr[24];
        #pragma unroll
        for (int i = 0; i < 6; ++i)
            *(float4*)&kr[i * 4] = *(const float4*)&kvbase[t * 24 + i * 4];
        float d = 0.f;
        #pragma unroll
        for (int c = 0; c < 21; ++c) d = fmaf(q[c], kr[c], d);
        d *= 0.21821789023599239f;   // 1/sqrt(21)
        sc[t] = d; m = fmaxf(m, d);
    }
    float sum = 0.f;
    #pragma unroll
    for (int t = 0; t < 10; ++t) { sc[t] = __expf(sc[t] - m); sum += sc[t]; }
    const float inv = 1.f / sum;

    float acc[21];
    #pragma unroll
    for (int c = 0; c < 21; ++c) acc[c] = 0.f;
    #pragma unroll
    for (int t = 0; t < 10; ++t) {
        float vr[24];
        #pragma unroll
        for (int i = 0; i < 6; ++i)
            *(float4*)&vr[i * 4] = *(const float4*)&kvbase[240 + t * 24 + i * 4];
        const float a = sc[t] * inv;
        #pragma unroll
        for (int c = 0; c < 21; ++c) acc[c] = fmaf(a, vr[c], acc[c]);
    }

    if (gs < B) {
        float* op = out + ((size_t)gs * 10 + r) * 21;
        #pragma unroll
        for (int c = 0; c < 21; ++c) op[c] = acc[c];
    }
}

extern "C" void kernel_launch(void* const* d_in, const int* in_sizes, int n_in,
                              void* d_out, int out_size, void* d_ws, size_t ws_size,
                              hipStream_t stream) {
    const float* state     = (const float*)d_in[0];
    const float* pos_intra = (const float*)d_in[1];
    const float* wq_i      = (const float*)d_in[2];
    const float* bq_i      = (const float*)d_in[3];
    const float* wk_i      = (const float*)d_in[4];
    const float* bk_i      = (const float*)d_in[5];
    const float* wv_i      = (const float*)d_in[6];
    const float* bv_i      = (const float*)d_in[7];
    const float* pos_inter = (const float*)d_in[8];
    const float* wq        = (const float*)d_in[9];
    const float* bq        = (const float*)d_in[10];
    const float* wk        = (const float*)d_in[11];
    const float* bk        = (const float*)d_in[12];
    const float* wv        = (const float*)d_in[13];
    const float* bv        = (const float*)d_in[14];
    float* outp = (float*)d_out;

    const int B = in_sizes[0] / 100;
    const int grid = (B + SPB - 1) / SPB;
    hipLaunchKernelGGL(crazy_attn_kernel, dim3(grid), dim3(NT), 0, stream,
                       state, pos_intra, wq_i, bq_i, wk_i, bk_i, wv_i, bv_i,
                       pos_inter, wq, bq, wk, bk, wv, bv, outp, B);
}

// Round 4
// 41.938 us; speedup vs baseline: 1.4543x; 1.4543x over previous
//
#include <hip/hip_runtime.h>

typedef __fp16 h2 __attribute__((ext_vector_type(2)));
typedef float f4 __attribute__((ext_vector_type(4)));

#if __has_builtin(__builtin_amdgcn_fdot2)
#define FDOT2(a, b, c) __builtin_amdgcn_fdot2((a), (b), (c), false)
#else
#define FDOT2(a, b, c) ((c) + (float)(a)[0] * (float)(b)[0] + (float)(a)[1] * (float)(b)[1])
#endif

#define SPB 32
#define NT  320
// per-sample LDS words: k = 10 rows * 12 words (24 f16) = 120,
//                       v = 10 rows * 24 words (f32)    = 240, skew 4 -> 364
#define KVW 364

__global__ __launch_bounds__(NT, 3)
void crazy_attn_kernel(const float* __restrict__ state,      // (B,100)
                       const float* __restrict__ pos_intra,  // (10,1)
                       const float* __restrict__ wq_i, const float* __restrict__ bq_i,
                       const float* __restrict__ wk_i, const float* __restrict__ bk_i,
                       const float* __restrict__ wv_i, const float* __restrict__ bv_i,
                       const float* __restrict__ pos_inter,  // (10,20)
                       const float* __restrict__ wq, const float* __restrict__ bq,
                       const float* __restrict__ wk, const float* __restrict__ bk,
                       const float* __restrict__ wv, const float* __restrict__ bv,
                       float* __restrict__ out, int B)
{
    __shared__ __attribute__((aligned(16))) float s_kv[SPB * KVW];  // 46592 B
    __shared__ __attribute__((aligned(16))) h2    s_w[63 * 12];     // 3024 B: [m][c][12 pairs], fp16 W^T, bias=pair10.x
    __shared__ __attribute__((aligned(16))) float s_pos[200];       // 800 B  (rows of 20f, 80B, 16B-aligned)

    const int tid  = threadIdx.x;
    const int samp = tid / 10;
    const int r    = tid - samp * 10;        // frame == inter row
    const int gs   = blockIdx.x * SPB + samp;
    const int gsc  = (gs < B) ? gs : (B - 1);

    // ---------------- stage 0: stage weights (f16, transposed, bias appended) + pos_inter
    #pragma unroll
    for (int i = tid; i < 200; i += NT) s_pos[i] = pos_inter[i];
    if (tid < 63) {
        const int m = tid / 21, c = tid - m * 21;
        const float* W  = (m == 0) ? wq : (m == 1) ? wk : wv;
        const float* Bb = (m == 0) ? bq : (m == 1) ? bk : bv;
        float t24[24];
        #pragma unroll
        for (int j = 0; j < 20; ++j) t24[j] = W[j * 21 + c];
        t24[20] = Bb[c]; t24[21] = 0.f; t24[22] = 0.f; t24[23] = 0.f;
        h2* dst = &s_w[tid * 12];
        #pragma unroll
        for (int p = 0; p < 12; ++p)
            dst[p] = __builtin_amdgcn_cvt_pkrtz(t24[2 * p], t24[2 * p + 1]);
    }

    // ---------------- stage A: intra attention (registers only; rank-1 score trick)
    float x[20];
    {
        const float* sp = state + (size_t)gsc * 100 + r * 10;
        float xv[10];
        #pragma unroll
        for (int t = 0; t < 10; ++t) xv[t] = sp[t] + pos_intra[t];
        float xmx = xv[0], xmn = xv[0];
        #pragma unroll
        for (int t = 1; t < 10; ++t) { xmx = fmaxf(xmx, xv[t]); xmn = fminf(xmn, xv[t]); }

        #pragma unroll
        for (int h = 0; h < 2; ++h) {
            const float wqh = wq_i[h], bqh = bq_i[h];
            const float wkh = wk_i[h];
            const float wvh = wv_i[h], bvh = bv_i[h];
            float vh[10], cs[10];
            #pragma unroll
            for (int t = 0; t < 10; ++t) {
                vh[t] = fmaf(xv[t], wvh, bvh);
                cs[t] = fmaf(xv[t], wqh, bqh) * wkh;   // q_s * wk; bias term cancels in softmax
            }
            #pragma unroll
            for (int s = 0; s < 10; ++s) {
                const float c  = cs[s];
                const float m  = c * ((c >= 0.f) ? xmx : xmn);   // exact max_t(c*x_t)
                const float cL = c * 1.44269504f;
                const float mL = m * 1.44269504f;
                float sum = 0.f, o = 0.f;
                #pragma unroll
                for (int t = 0; t < 10; ++t) {
                    const float e = __builtin_amdgcn_exp2f(fmaf(cL, xv[t], -mL));
                    sum += e; o = fmaf(e, vh[t], o);
                }
                x[s * 2 + h] = o * __builtin_amdgcn_rcpf(sum);
            }
        }
    }

    __syncthreads();   // weights + pos staged

    // ---------------- stage B: q/k/v projections via fp16 dot2
    float* kvbase = &s_kv[samp * KVW];
    h2 xp[11];
    {
        float px[20];
        #pragma unroll
        for (int i = 0; i < 5; ++i) *(f4*)&px[i * 4] = *(const f4*)&s_pos[r * 20 + i * 4];
        #pragma unroll
        for (int p = 0; p < 10; ++p)
            xp[p] = __builtin_amdgcn_cvt_pkrtz(x[2 * p] + px[2 * p], x[2 * p + 1] + px[2 * p + 1]);
        xp[10] = __builtin_amdgcn_cvt_pkrtz(1.0f, 0.0f);   // bias input pair
    }

    float q[21];
    #pragma unroll
    for (int c = 0; c < 21; ++c) {
        union { uint4 u[3]; h2 h[12]; } W;
        const uint4* wrow = (const uint4*)&s_w[c * 12];
        W.u[0] = wrow[0]; W.u[1] = wrow[1]; W.u[2] = wrow[2];
        float a = 0.f;
        #pragma unroll
        for (int p = 0; p < 11; ++p) a = FDOT2(xp[p], W.h[p], a);
        q[c] = a;
    }
    {   // k row -> LDS (fp16)
        float kr[21];
        #pragma unroll
        for (int c = 0; c < 21; ++c) {
            union { uint4 u[3]; h2 h[12]; } W;
            const uint4* wrow = (const uint4*)&s_w[(21 + c) * 12];
            W.u[0] = wrow[0]; W.u[1] = wrow[1]; W.u[2] = wrow[2];
            float a = 0.f;
            #pragma unroll
            for (int p = 0; p < 11; ++p) a = FDOT2(xp[p], W.h[p], a);
            kr[c] = a;
        }
        union { uint4 u[3]; h2 h[12]; } K;
        #pragma unroll
        for (int p = 0; p < 10; ++p) K.h[p] = __builtin_amdgcn_cvt_pkrtz(kr[2 * p], kr[2 * p + 1]);
        K.h[10] = __builtin_amdgcn_cvt_pkrtz(kr[20], 0.f);
        K.h[11] = __builtin_amdgcn_cvt_pkrtz(0.f, 0.f);
        uint4* kd = (uint4*)&kvbase[r * 12];
        kd[0] = K.u[0]; kd[1] = K.u[1]; kd[2] = K.u[2];
    }
    {   // v row -> LDS (f32)
        float vr[24];
        #pragma unroll
        for (int c = 0; c < 21; ++c) {
            union { uint4 u[3]; h2 h[12]; } W;
            const uint4* wrow = (const uint4*)&s_w[(42 + c) * 12];
            W.u[0] = wrow[0]; W.u[1] = wrow[1]; W.u[2] = wrow[2];
            float a = 0.f;
            #pragma unroll
            for (int p = 0; p < 11; ++p) a = FDOT2(xp[p], W.h[p], a);
            vr[c] = a;
        }
        vr[21] = vr[22] = vr[23] = 0.f;
        #pragma unroll
        for (int i = 0; i < 6; ++i)
            *(f4*)&kvbase[120 + r * 24 + i * 4] = *(const f4*)&vr[i * 4];
    }

    // q -> fp16 pairs for the score dot
    h2 qp[11];
    #pragma unroll
    for (int p = 0; p < 10; ++p) qp[p] = __builtin_amdgcn_cvt_pkrtz(q[2 * p], q[2 * p + 1]);
    qp[10] = __builtin_amdgcn_cvt_pkrtz(q[20], 0.f);

    __syncthreads();   // k/v staged

    // ---------------- stage C: inter attention
    float sc[10], m = -1e30f;
    #pragma unroll
    for (int t = 0; t < 10; ++t) {
        union { uint4 u[3]; h2 h[12]; } K;
        const uint4* kr_ = (const uint4*)&kvbase[t * 12];
        K.u[0] = kr_[0]; K.u[1] = kr_[1]; K.u[2] = kr_[2];
        float a = 0.f;
        #pragma unroll
        for (int p = 0; p < 11; ++p) a = FDOT2(qp[p], K.h[p], a);
        a *= 0.21821789023599239f;   // 1/sqrt(21)
        sc[t] = a; m = fmaxf(m, a);
    }
    float sum = 0.f;
    #pragma unroll
    for (int t = 0; t < 10; ++t) {
        sc[t] = __builtin_amdgcn_exp2f((sc[t] - m) * 1.44269504f);
        sum += sc[t];
    }
    const float inv = __builtin_amdgcn_rcpf(sum);

    float acc[21];
    #pragma unroll
    for (int c = 0; c < 21; ++c) acc[c] = 0.f;
    #pragma unroll
    for (int t = 0; t < 10; ++t) {
        float vr[24];
        #pragma unroll
        for (int i = 0; i < 6; ++i)
            *(f4*)&vr[i * 4] = *(const f4*)&kvbase[120 + t * 24 + i * 4];
        const float a = sc[t] * inv;
        #pragma unroll
        for (int c = 0; c < 21; ++c) acc[c] = fmaf(a, vr[c], acc[c]);
    }

    if (gs < B) {
        float* op = out + ((size_t)gs * 10 + r) * 21;
        #pragma unroll
        for (int c = 0; c < 21; ++c) op[c] = acc[c];
    }
}

extern "C" void kernel_launch(void* const* d_in, const int* in_sizes, int n_in,
                              void* d_out, int out_size, void* d_ws, size_t ws_size,
                              hipStream_t stream) {
    const float* state     = (const float*)d_in[0];
    const float* pos_intra = (const float*)d_in[1];
    const float* wq_i      = (const float*)d_in[2];
    const float* bq_i      = (const float*)d_in[3];
    const float* wk_i      = (const float*)d_in[4];
    const float* bk_i      = (const float*)d_in[5];
    const float* wv_i      = (const float*)d_in[6];
    const float* bv_i      = (const float*)d_in[7];
    const float* pos_inter = (const float*)d_in[8];
    const float* wq        = (const float*)d_in[9];
    const float* bq        = (const float*)d_in[10];
    const float* wk        = (const float*)d_in[11];
    const float* bk        = (const float*)d_in[12];
    const float* wv        = (const float*)d_in[13];
    const float* bv        = (const float*)d_in[14];
    float* outp = (float*)d_out;

    const int B = in_sizes[0] / 100;
    const int grid = (B + SPB - 1) / SPB;
    hipLaunchKernelGGL(crazy_attn_kernel, dim3(grid), dim3(NT), 0, stream,
                       state, pos_intra, wq_i, bq_i, wk_i, bk_i, wv_i, bv_i,
                       pos_inter, wq, bq, wk, bk, wv, bv, outp, B);
}

// Round 5
// 30.861 us; speedup vs baseline: 1.9763x; 1.3589x over previous
//
#include <hip/hip_runtime.h>

typedef __fp16 h2 __attribute__((ext_vector_type(2)));
typedef float f4 __attribute__((ext_vector_type(4)));

#if __has_builtin(__builtin_amdgcn_fdot2)
#define FDOT2(a, b, c) __builtin_amdgcn_fdot2((a), (b), (c), false)
#else
#define FDOT2(a, b, c) ((c) + (float)(a)[0] * (float)(b)[0] + (float)(a)[1] * (float)(b)[1])
#endif

#define SPB 32
#define NT  320
// per-sample LDS words: k = 10 rows * 12 words (24 f16) = 120,
//                       v = 10 rows * 24 words (f32)    = 240, skew 4 -> 364
#define KVW 364
#define OUTW (SPB * 210)   // 6720 floats = 26880 B, aliases s_kv after stage C

__global__ __launch_bounds__(NT, 3)
void crazy_attn_kernel(const float* __restrict__ state,      // (B,100)
                       const float* __restrict__ pos_intra,  // (10,1)
                       const float* __restrict__ wq_i, const float* __restrict__ bq_i,
                       const float* __restrict__ wk_i, const float* __restrict__ bk_i,
                       const float* __restrict__ wv_i, const float* __restrict__ bv_i,
                       const float* __restrict__ pos_inter,  // (10,20)
                       const float* __restrict__ wq, const float* __restrict__ bq,
                       const float* __restrict__ wk, const float* __restrict__ bk,
                       const float* __restrict__ wv, const float* __restrict__ bv,
                       float* __restrict__ out, int B)
{
    __shared__ __attribute__((aligned(16))) float s_kv[SPB * KVW];  // 46592 B (>= OUTW*4)
    __shared__ __attribute__((aligned(16))) h2    s_w[63 * 12];     // fp16 W^T, bias appended
    __shared__ __attribute__((aligned(16))) float s_pos[200];

    const int tid  = threadIdx.x;
    const int samp = tid / 10;
    const int r    = tid - samp * 10;        // frame == inter row
    const int gs   = blockIdx.x * SPB + samp;
    const int gsc  = (gs < B) ? gs : (B - 1);

    // ---------------- stage 0: stage weights (f16, transposed, bias appended) + pos_inter
    #pragma unroll
    for (int i = tid; i < 200; i += NT) s_pos[i] = pos_inter[i];
    if (tid < 63) {
        const int m = tid / 21, c = tid - m * 21;
        const float* W  = (m == 0) ? wq : (m == 1) ? wk : wv;
        const float* Bb = (m == 0) ? bq : (m == 1) ? bk : bv;
        float t24[24];
        #pragma unroll
        for (int j = 0; j < 20; ++j) t24[j] = W[j * 21 + c];
        t24[20] = Bb[c]; t24[21] = 0.f; t24[22] = 0.f; t24[23] = 0.f;
        h2* dst = &s_w[tid * 12];
        #pragma unroll
        for (int p = 0; p < 12; ++p)
            dst[p] = __builtin_amdgcn_cvt_pkrtz(t24[2 * p], t24[2 * p + 1]);
    }

    // ---------------- stage A: intra attention (registers only; rank-1 score trick)
    float x[20];
    {
        const float* sp = state + (size_t)gsc * 100 + r * 10;
        float xv[10];
        #pragma unroll
        for (int t = 0; t < 10; ++t) xv[t] = sp[t] + pos_intra[t];
        float xmx = xv[0], xmn = xv[0];
        #pragma unroll
        for (int t = 1; t < 10; ++t) { xmx = fmaxf(xmx, xv[t]); xmn = fminf(xmn, xv[t]); }

        #pragma unroll
        for (int h = 0; h < 2; ++h) {
            const float wqh = wq_i[h], bqh = bq_i[h];
            const float wkh = wk_i[h];
            const float wvh = wv_i[h], bvh = bv_i[h];
            float vh[10], cs[10];
            #pragma unroll
            for (int t = 0; t < 10; ++t) {
                vh[t] = fmaf(xv[t], wvh, bvh);
                cs[t] = fmaf(xv[t], wqh, bqh) * wkh;   // bias term cancels in softmax
            }
            #pragma unroll
            for (int s = 0; s < 10; ++s) {
                const float c  = cs[s];
                const float m  = c * ((c >= 0.f) ? xmx : xmn);   // exact max_t(c*x_t)
                const float cL = c * 1.44269504f;
                const float mL = m * 1.44269504f;
                float sum = 0.f, o = 0.f;
                #pragma unroll
                for (int t = 0; t < 10; ++t) {
                    const float e = __builtin_amdgcn_exp2f(fmaf(cL, xv[t], -mL));
                    sum += e; o = fmaf(e, vh[t], o);
                }
                x[s * 2 + h] = o * __builtin_amdgcn_rcpf(sum);
            }
        }
    }

    __syncthreads();   // weights + pos staged

    // ---------------- stage B: q/k/v projections via fp16 dot2
    float* kvbase = &s_kv[samp * KVW];
    h2 xp[11];
    {
        float px[20];
        #pragma unroll
        for (int i = 0; i < 5; ++i) *(f4*)&px[i * 4] = *(const f4*)&s_pos[r * 20 + i * 4];
        #pragma unroll
        for (int p = 0; p < 10; ++p)
            xp[p] = __builtin_amdgcn_cvt_pkrtz(x[2 * p] + px[2 * p], x[2 * p + 1] + px[2 * p + 1]);
        xp[10] = __builtin_amdgcn_cvt_pkrtz(1.0f, 0.0f);   // bias input pair
    }

    float q[21];
    #pragma unroll
    for (int c = 0; c < 21; ++c) {
        union { uint4 u[3]; h2 h[12]; } W;
        const uint4* wrow = (const uint4*)&s_w[c * 12];
        W.u[0] = wrow[0]; W.u[1] = wrow[1]; W.u[2] = wrow[2];
        float a = 0.f;
        #pragma unroll
        for (int p = 0; p < 11; ++p) a = FDOT2(xp[p], W.h[p], a);
        q[c] = a;
    }
    {   // k row -> LDS (fp16)
        float kr[21];
        #pragma unroll
        for (int c = 0; c < 21; ++c) {
            union { uint4 u[3]; h2 h[12]; } W;
            const uint4* wrow = (const uint4*)&s_w[(21 + c) * 12];
            W.u[0] = wrow[0]; W.u[1] = wrow[1]; W.u[2] = wrow[2];
            float a = 0.f;
            #pragma unroll
            for (int p = 0; p < 11; ++p) a = FDOT2(xp[p], W.h[p], a);
            kr[c] = a;
        }
        union { uint4 u[3]; h2 h[12]; } K;
        #pragma unroll
        for (int p = 0; p < 10; ++p) K.h[p] = __builtin_amdgcn_cvt_pkrtz(kr[2 * p], kr[2 * p + 1]);
        K.h[10] = __builtin_amdgcn_cvt_pkrtz(kr[20], 0.f);
        K.h[11] = __builtin_amdgcn_cvt_pkrtz(0.f, 0.f);
        uint4* kd = (uint4*)&kvbase[r * 12];
        kd[0] = K.u[0]; kd[1] = K.u[1]; kd[2] = K.u[2];
    }
    {   // v row -> LDS (f32)
        float vr[24];
        #pragma unroll
        for (int c = 0; c < 21; ++c) {
            union { uint4 u[3]; h2 h[12]; } W;
            const uint4* wrow = (const uint4*)&s_w[(42 + c) * 12];
            W.u[0] = wrow[0]; W.u[1] = wrow[1]; W.u[2] = wrow[2];
            float a = 0.f;
            #pragma unroll
            for (int p = 0; p < 11; ++p) a = FDOT2(xp[p], W.h[p], a);
            vr[c] = a;
        }
        vr[21] = vr[22] = vr[23] = 0.f;
        #pragma unroll
        for (int i = 0; i < 6; ++i)
            *(f4*)&kvbase[120 + r * 24 + i * 4] = *(const f4*)&vr[i * 4];
    }

    // q -> fp16 pairs for the score dot
    h2 qp[11];
    #pragma unroll
    for (int p = 0; p < 10; ++p) qp[p] = __builtin_amdgcn_cvt_pkrtz(q[2 * p], q[2 * p + 1]);
    qp[10] = __builtin_amdgcn_cvt_pkrtz(q[20], 0.f);

    __syncthreads();   // k/v staged

    // ---------------- stage C: inter attention
    float sc[10], m = -1e30f;
    #pragma unroll
    for (int t = 0; t < 10; ++t) {
        union { uint4 u[3]; h2 h[12]; } K;
        const uint4* kr_ = (const uint4*)&kvbase[t * 12];
        K.u[0] = kr_[0]; K.u[1] = kr_[1]; K.u[2] = kr_[2];
        float a = 0.f;
        #pragma unroll
        for (int p = 0; p < 11; ++p) a = FDOT2(qp[p], K.h[p], a);
        a *= 0.21821789023599239f;   // 1/sqrt(21)
        sc[t] = a; m = fmaxf(m, a);
    }
    float sum = 0.f;
    #pragma unroll
    for (int t = 0; t < 10; ++t) {
        sc[t] = __builtin_amdgcn_exp2f((sc[t] - m) * 1.44269504f);
        sum += sc[t];
    }
    const float inv = __builtin_amdgcn_rcpf(sum);

    float acc[21];
    #pragma unroll
    for (int c = 0; c < 21; ++c) acc[c] = 0.f;
    #pragma unroll
    for (int t = 0; t < 10; ++t) {
        float vr[24];
        #pragma unroll
        for (int i = 0; i < 6; ++i)
            *(f4*)&vr[i * 4] = *(const f4*)&kvbase[120 + t * 24 + i * 4];
        const float a = sc[t] * inv;
        #pragma unroll
        for (int c = 0; c < 21; ++c) acc[c] = fmaf(a, vr[c], acc[c]);
    }

    // ---------------- epilogue: stage rows in LDS, then coalesced block copy
    __syncthreads();   // all stage-C k/v reads done; safe to overwrite s_kv
    {
        float* s_out = s_kv;               // alias (26880 B <= 46592 B)
        float* dst = &s_out[samp * 210 + r * 21];
        #pragma unroll
        for (int c = 0; c < 21; ++c) dst[c] = acc[c];
    }
    __syncthreads();

    {
        const int samp0 = blockIdx.x * SPB;
        const int nvalid = ((B - samp0) < SPB ? (B - samp0) : SPB) * 210;  // floats in this block
        float* gdst = out + (size_t)samp0 * 210;
        const f4* src4 = (const f4*)s_kv;
        if (nvalid == OUTW) {
            #pragma unroll
            for (int i = tid; i < OUTW / 4; i += NT)
                *(f4*)&gdst[i * 4] = src4[i];
        } else {
            for (int i = tid; i < nvalid; i += NT) gdst[i] = s_kv[i];
        }
    }
}

extern "C" void kernel_launch(void* const* d_in, const int* in_sizes, int n_in,
                              void* d_out, int out_size, void* d_ws, size_t ws_size,
                              hipStream_t stream) {
    const float* state     = (const float*)d_in[0];
    const float* pos_intra = (const float*)d_in[1];
    const float* wq_i      = (const float*)d_in[2];
    const float* bq_i      = (const float*)d_in[3];
    const float* wk_i      = (const float*)d_in[4];
    const float* bk_i      = (const float*)d_in[5];
    const float* wv_i      = (const float*)d_in[6];
    const float* bv_i      = (const float*)d_in[7];
    const float* pos_inter = (const float*)d_in[8];
    const float* wq        = (const float*)d_in[9];
    const float* bq        = (const float*)d_in[10];
    const float* wk        = (const float*)d_in[11];
    const float* bk        = (const float*)d_in[12];
    const float* wv        = (const float*)d_in[13];
    const float* bv        = (const float*)d_in[14];
    float* outp = (float*)d_out;

    const int B = in_sizes[0] / 100;
    const int grid = (B + SPB - 1) / SPB;
    hipLaunchKernelGGL(crazy_attn_kernel, dim3(grid), dim3(NT), 0, stream,
                       state, pos_intra, wq_i, bq_i, wk_i, bk_i, wv_i, bv_i,
                       pos_inter, wq, bq, wk, bk, wv, bv, outp, B);
}